// Round 1
// baseline (582.327 us; speedup 1.0000x reference)
//
#include <hip/hip_runtime.h>
#include <hip/hip_bf16.h>
#include <stdint.h>

#define EPS 1e-5f

typedef int v4i __attribute__((ext_vector_type(4)));
typedef int v16i __attribute__((ext_vector_type(16)));
typedef const __attribute__((address_space(1))) void g_void;
typedef __attribute__((address_space(3))) void l_void;

// ---------------- block reductions ----------------
__device__ inline float block_max_nw(float v, int nw) {
    __shared__ float s[8];
#pragma unroll
    for (int o = 32; o; o >>= 1) v = fmaxf(v, __shfl_xor(v, o, 64));
    if ((threadIdx.x & 63) == 0) s[threadIdx.x >> 6] = v;
    __syncthreads();
    float m = s[0];
    for (int i = 1; i < nw; ++i) m = fmaxf(m, s[i]);
    return m;
}

__device__ inline float block_sum64x4(float v) {
    __shared__ float s[4];
#pragma unroll
    for (int o = 32; o; o >>= 1) v += __shfl_xor(v, o, 64);
    if ((threadIdx.x & 63) == 0) s[threadIdx.x >> 6] = v;
    __syncthreads();
    return s[0] + s[1] + s[2] + s[3];
}

// ---------------- |w| sum: stage 1 (deterministic partials, fixed grid 1024) ----
__global__ __launch_bounds__(256) void abs_sum_part_k(const float4* __restrict__ w,
                                                      int n4, float* __restrict__ part) {
    float s = 0.0f;
    for (int i = blockIdx.x * 256 + threadIdx.x; i < n4; i += 1024 * 256) {
        float4 v = w[i];
        s += fabsf(v.x) + fabsf(v.y) + fabsf(v.z) + fabsf(v.w);
    }
    s = block_sum64x4(s);
    if (threadIdx.x == 0) part[blockIdx.x] = s;
}

// ---------------- |w| sum: stage 2 ----------
__global__ __launch_bounds__(256) void abs_sum_final_k(const float* __restrict__ parts,
                                                       float* __restrict__ sums) {
    const float* p = parts + blockIdx.x * 1024;
    const int t = threadIdx.x;
    float s = p[t] + p[t + 256] + p[t + 512] + p[t + 768];
    s = block_sum64x4(s);
    if (t == 0) sums[blockIdx.x] = s;
}

// ---------------- ternary weight quantization ----------------
__global__ __launch_bounds__(256) void wquant_k(const float4* __restrict__ w,
                                                char4* __restrict__ q,
                                                const float* __restrict__ sum) {
    const float mean = fmaxf(sum[0] * (1.0f / 3145728.0f), EPS);
    const float scale = 1.0f / mean;
    const int i = blockIdx.x * 256 + threadIdx.x;
    float4 v = w[i];
    char4 c;
    c.x = (signed char)(int)fmaxf(fminf(rintf(v.x * scale), 1.0f), -1.0f);
    c.y = (signed char)(int)fmaxf(fminf(rintf(v.y * scale), 1.0f), -1.0f);
    c.z = (signed char)(int)fmaxf(fminf(rintf(v.z * scale), 1.0f), -1.0f);
    c.w = (signed char)(int)fmaxf(fminf(rintf(v.w * scale), 1.0f), -1.0f);
    q[i] = c;
}

// ---------------- per-token int8 quantization of x (rows of 1024 fp32) ----------
__global__ __launch_bounds__(256) void aquant_k(const float4* __restrict__ x,
                                                char4* __restrict__ q,
                                                float* __restrict__ deq) {
    const int row = blockIdx.x, t = threadIdx.x;
    const float4 v = x[(size_t)row * 256 + t];
    float m = fmaxf(fmaxf(fabsf(v.x), fabsf(v.y)), fmaxf(fabsf(v.z), fabsf(v.w)));
    m = block_max_nw(m, 4);
    const float mc = fmaxf(m, EPS);
    const float sc = 127.0f / mc;
    char4 c;
    c.x = (signed char)(int)fmaxf(fminf(rintf(v.x * sc), 127.0f), -128.0f);
    c.y = (signed char)(int)fmaxf(fminf(rintf(v.y * sc), 127.0f), -128.0f);
    c.z = (signed char)(int)fmaxf(fminf(rintf(v.z * sc), 127.0f), -128.0f);
    c.w = (signed char)(int)fmaxf(fminf(rintf(v.w * sc), 127.0f), -128.0f);
    q[(size_t)row * 256 + t] = c;
    if (t == 0) deq[row] = mc / 127.0f;
}

// ---------------- per-token quant of bf16 hidden rows (3072), IN PLACE ----------
__global__ __launch_bounds__(384) void hquant_k(unsigned short* __restrict__ hid,
                                                float* __restrict__ deq) {
    const size_t row = blockIdx.x;
    const int t = threadIdx.x;
    unsigned short* rp = hid + row * 3072;
    const uint4 u = ((const uint4*)rp)[t];
    float v[8];
    {
        uint32_t uu[4] = {u.x, u.y, u.z, u.w};
#pragma unroll
        for (int i = 0; i < 4; ++i) {
            uint32_t lo = uu[i] << 16, hi = uu[i] & 0xFFFF0000u;
            v[2 * i]     = __uint_as_float(lo);
            v[2 * i + 1] = __uint_as_float(hi);
        }
    }
    float m = 0.0f;
#pragma unroll
    for (int i = 0; i < 8; ++i) m = fmaxf(m, fabsf(v[i]));
    m = block_max_nw(m, 6);   // contains __syncthreads(): loads done before stores
    const float mc = fmaxf(m, EPS);
    const float sc = 127.0f / mc;
    uint32_t p0 = 0, p1 = 0;
#pragma unroll
    for (int i = 0; i < 4; ++i) {
        int c = (int)fminf(rintf(v[i] * sc), 127.0f);          // v >= 0 (relu^2)
        p0 |= (uint32_t)(c & 255) << (8 * i);
    }
#pragma unroll
    for (int i = 0; i < 4; ++i) {
        int c = (int)fminf(rintf(v[4 + i] * sc), 127.0f);
        p1 |= (uint32_t)(c & 255) << (8 * i);
    }
    uint2 pk; pk.x = p0; pk.y = p1;
    ((uint2*)rp)[t] = pk;
    if (t == 0) deq[row] = mc / 127.0f;
}

// ---------------- int8 GEMM: C[m][n] = sum_k A[m][k]*B[n][k] ----------------
// 256x256 tile, BK=128, 512 threads = 8 waves (2M x 4N), wave tile 128x64 as
// 4x2 tiles of v_mfma_i32_32x32x32_i8. Double-buffered LDS (128 KB), counted
// vmcnt pipeline (T3+T4): raw s_barrier only, global_load_lds for tile t+2
// stays in flight across both barriers of tile t+1; vmcnt(8) waits only for
// the tile about to be computed. LDS rows 128 B, 16 B chunks XOR-swizzled by
// (row&7); swizzle folded into the staging lanes' GLOBAL addresses
// (global_load_lds LDS dest is lane-contiguous). XCD-aware map: xcd = blk&7.
template <bool RELU2, typename OutT>
__global__ __launch_bounds__(512, 2) void gemm_i8(
    const int8_t* __restrict__ A, int lda,        // row pitch in bytes
    const int8_t* __restrict__ B, int ldb,
    OutT* __restrict__ O, int ldo,                // pitch in elements
    const float* __restrict__ rowDeq,
    const float* __restrict__ sumPtr,
    const float* __restrict__ bias,
    int K, int nTiles) {
    __shared__ __align__(16) char As[2][32768];   // 64 KB (2 x 256x128)
    __shared__ __align__(16) char Bs[2][32768];   // 64 KB
    const int t = threadIdx.x;
    const int lane = t & 63;
    const int w = t >> 6;                         // wave 0..7
    const int wm = w >> 2;                        // 0..1
    const int wn = w & 3;                         // 0..3
    const int xcd = blockIdx.x & 7;
    const int sb = blockIdx.x >> 3;
    const int bm = xcd + 8 * (sb / nTiles);
    const int bn = sb % nTiles;
    const long m0 = (long)bm * 256;
    const long n0 = (long)bn * 256;

    v16i acc[4][2];
#pragma unroll
    for (int i = 0; i < 4; ++i)
#pragma unroll
        for (int j = 0; j < 2; ++j) acc[i][j] = (v16i)(0);

    const int r32 = lane & 31;
    const int h = lane >> 5;
    const int swz = r32 & 7;
    const int srow = lane >> 3;                   // 0..7 within 8-row stage group
    const int scol = ((lane & 7) ^ srow) * 16;    // swizzled k-offset for staging
    const int mloc = wm * 128;
    const int nloc = wn * 64;

    // staging: round r covers rows r*64 + w*8 + srow (row&7 == srow)
    const int8_t* pa = A + (m0 + w * 8 + srow) * (long)lda + scol;
    const int8_t* pb = B + (n0 + w * 8 + srow) * (long)ldb + scol;

    // swizzled chunk byte-offsets for fragment reads, per k-step
    int cs[4];
#pragma unroll
    for (int ks = 0; ks < 4; ++ks) cs[ks] = ((ks * 2 + h) ^ swz) * 16;

    const int NT = K >> 7;                        // K-tiles of 128

    auto STAGE = [&](int tt, int buf) {           // 8 global_load_lds per wave
        const long ko = (long)tt << 7;
#pragma unroll
        for (int r = 0; r < 4; ++r)
            __builtin_amdgcn_global_load_lds((g_void*)(pa + (long)(r * 64) * lda + ko),
                                             (l_void*)(As[buf] + r * 8192 + w * 1024), 16, 0, 0);
#pragma unroll
        for (int r = 0; r < 4; ++r)
            __builtin_amdgcn_global_load_lds((g_void*)(pb + (long)(r * 64) * ldb + ko),
                                             (l_void*)(Bs[buf] + r * 8192 + w * 1024), 16, 0, 0);
    };

    // prologue: tiles 0 and 1 in flight; wait only for tile 0 (8 of 16)
    STAGE(0, 0);
    STAGE(1, 1);
    asm volatile("s_waitcnt vmcnt(8)" ::: "memory");
    __builtin_amdgcn_s_barrier();
    asm volatile("" ::: "memory");

    for (int tt = 0; tt < NT; ++tt) {
        const int cur = tt & 1;
        // hoist ALL fragment reads for this K-tile (frees buf[cur] at the barrier)
        v4i af[4][4], bf[2][4];
#pragma unroll
        for (int ks = 0; ks < 4; ++ks) {
#pragma unroll
            for (int mt = 0; mt < 4; ++mt)
                af[mt][ks] = *(const v4i*)(As[cur] + (mloc + mt * 32 + r32) * 128 + cs[ks]);
#pragma unroll
            for (int nt = 0; nt < 2; ++nt)
                bf[nt][ks] = *(const v4i*)(Bs[cur] + (nloc + nt * 32 + r32) * 128 + cs[ks]);
        }
        asm volatile("s_waitcnt lgkmcnt(0)" ::: "memory");  // reads retired
        __builtin_amdgcn_s_barrier();                       // B1: buf[cur] free
        asm volatile("" ::: "memory");
        const bool pf = (tt + 2 < NT);
        if (pf) STAGE(tt + 2, cur);                         // overwrite buf[cur]
        __builtin_amdgcn_s_setprio(1);
#pragma unroll
        for (int ks = 0; ks < 4; ++ks)
#pragma unroll
            for (int mt = 0; mt < 4; ++mt)
#pragma unroll
                for (int nt = 0; nt < 2; ++nt)
                    acc[mt][nt] = __builtin_amdgcn_mfma_i32_32x32x32_i8(
                        af[mt][ks], bf[nt][ks], acc[mt][nt], 0, 0, 0);
        __builtin_amdgcn_s_setprio(0);
        // wait for tile tt+1 only; tile tt+2's 8 loads remain in flight
        if (pf) asm volatile("s_waitcnt vmcnt(8)" ::: "memory");
        else    asm volatile("s_waitcnt vmcnt(0)" ::: "memory");
        __builtin_amdgcn_s_barrier();                       // B2: buf[cur^1] ready
        asm volatile("" ::: "memory");
    }

    // epilogue: C/D layout col = lane&31, row = (reg&3) + 8*(reg>>2) + 4*(lane>>5)
    const float wdeq = fmaxf(sumPtr[0] * (1.0f / 3145728.0f), EPS);
#pragma unroll
    for (int mt = 0; mt < 4; ++mt) {
#pragma unroll
        for (int g = 0; g < 4; ++g) {
#pragma unroll
            for (int rr = 0; rr < 4; ++rr) {
                const long row = m0 + mloc + mt * 32 + g * 8 + h * 4 + rr;
                const float rs = rowDeq[row] * wdeq;
#pragma unroll
                for (int nt = 0; nt < 2; ++nt) {
                    const long col = n0 + nloc + nt * 32 + r32;
                    float val = (float)acc[mt][nt][g * 4 + rr] * rs + bias[col];
                    if (RELU2) {
                        val = fmaxf(val, 0.0f);
                        val = val * val;
                    }
                    O[row * (long)ldo + col] = (OutT)val;
                }
            }
        }
    }
}

// ---------------- launch ----------------
extern "C" void kernel_launch(void* const* d_in, const int* in_sizes, int n_in,
                              void* d_out, int out_size, void* d_ws, size_t ws_size,
                              hipStream_t stream) {
    const float* x      = (const float*)d_in[0];   // [32768,1024]
    const float* up_w   = (const float*)d_in[1];   // [3072,1024]
    const float* up_b   = (const float*)d_in[2];   // [3072]
    const float* down_w = (const float*)d_in[3];   // [1024,3072]
    const float* down_b = (const float*)d_in[4];   // [1024]

    // ws: sums 256B | parts 8KB | qw_dn 3MB | deqh 128KB | hidden bf16 201MB
    char* ws = (char*)d_ws;
    float*  sums   = (float*)ws;
    float*  parts  = (float*)(ws + 256);
    int8_t* qw_dn  = (int8_t*)(ws + 256 + 8192);
    float*  deqh   = (float*)(ws + 256 + 8192 + 3145728);
    __hip_bfloat16* hidden = (__hip_bfloat16*)(ws + 256 + 8192 + 3145728 + 131072);

    // d_out head as phase-1 scratch (dead before GEMM2 writes)
    int8_t* qx    = (int8_t*)d_out;                      // 33.5MB
    int8_t* qw_up = qx + 33554432;                       // 3MB
    float*  deqx  = (float*)(qx + 33554432 + 3145728);   // 128KB

    abs_sum_part_k<<<1024, 256, 0, stream>>>((const float4*)up_w, 786432, parts);
    abs_sum_part_k<<<1024, 256, 0, stream>>>((const float4*)down_w, 786432, parts + 1024);
    abs_sum_final_k<<<2, 256, 0, stream>>>(parts, sums);

    wquant_k<<<3072, 256, 0, stream>>>((const float4*)up_w, (char4*)qw_up, &sums[0]);
    wquant_k<<<3072, 256, 0, stream>>>((const float4*)down_w, (char4*)qw_dn, &sums[1]);
    aquant_k<<<32768, 256, 0, stream>>>((const float4*)x, (char4*)qx, deqx);

    // GEMM1: [32768,1024] x [3072,1024]^T -> hidden bf16 (relu^2 fused)
    // grid: 128 m-tiles x 12 n-tiles = 1536 blocks (divisible by 8 XCDs)
    gemm_i8<true, __hip_bfloat16><<<1536, 512, 0, stream>>>(
        qx, 1024, qw_up, 1024, hidden, 3072, deqx, &sums[0], up_b, 1024, 12);
    // quantize hidden rows in place (int8 overlaid, pitch 6144 B)
    hquant_k<<<32768, 384, 0, stream>>>((unsigned short*)hidden, deqh);
    // GEMM2: [32768,3072] x [1024,3072]^T -> d_out fp32
    // grid: 128 m-tiles x 4 n-tiles = 512 blocks
    gemm_i8<false, float><<<512, 512, 0, stream>>>(
        (const int8_t*)hidden, 6144, qw_dn, 3072, (float*)d_out, 1024,
        deqh, &sums[1], down_b, 3072, 4);
}